// Round 20
// baseline (90.079 us; speedup 1.0000x reference)
//
#include <hip/hip_runtime.h>
#include <stdint.h>

#define NB 2
#define N1 2048
#define N2 8192
#define INF_ 128
#define F 64
#define ALPHA 0.2f
#define CAP_E 640   // per-row capacity (mult of 16); mean 409.6 sd 19.7 (+11.7 sigma)
#define CAP_N 192   // per-col capacity (mult of 16); mean 102.4 sd  9.9

// bf16 helpers
__device__ __forceinline__ float bf2f(unsigned short u) {
    return __uint_as_float((unsigned int)u << 16);
}
__device__ __forceinline__ unsigned short f2bf(float f) {
    unsigned int u = __float_as_uint(f);
    u += 0x7FFF + ((u >> 16) & 1);
    return (unsigned short)(u >> 16);
}
__device__ __forceinline__ float blo(unsigned int d) { return __uint_as_float(d << 16); }
__device__ __forceinline__ float bhi(unsigned int d) { return __uint_as_float(d & 0xFFFF0000u); }

// ---------------------------------------------------------------------------
// k_mask_csr: adj (0/1 fp32, 128 MB) -> bits (permuted words) + idxE + cntE.
// Measured (R13): ~20-25 us warm — near stream floor. Unchanged.
// ---------------------------------------------------------------------------
__global__ __launch_bounds__(256) void k_mask_csr(
    const float4* __restrict__ adj4, uint64_t* __restrict__ bits,
    uint16_t* __restrict__ idxE, int* __restrict__ cntE)
{
    __shared__ uint64_t sBits[128];
    __shared__ uint16_t sIdx[CAP_E];
    __shared__ int      sCnt[4];
    int tid  = threadIdx.x;
    int lane = tid & 63;
    int w    = tid >> 6;
    int row  = blockIdx.x;               // 4096 blocks = 4096 rows
    int b    = row >> 11;

    const float4* ar = adj4 + (size_t)row * (N2 / 4) + (size_t)w * 512 + lane;
    float4 v[8];
    #pragma unroll
    for (int it = 0; it < 8; ++it) v[it] = ar[it * 64];
    int cnt = 0;
    #pragma unroll
    for (int it = 0; it < 8; ++it) {
        unsigned long long m0 = __ballot(v[it].x != 0.0f);
        unsigned long long m1 = __ballot(v[it].y != 0.0f);
        unsigned long long m2 = __ballot(v[it].z != 0.0f);
        unsigned long long m3 = __ballot(v[it].w != 0.0f);
        if (lane == 0) {
            uint64_t* o = &sBits[w * 32 + it * 4];
            o[0] = m0; o[1] = m1; o[2] = m2; o[3] = m3;
        }
        cnt += (int)__popcll(m0) + (int)__popcll(m1)
             + (int)__popcll(m2) + (int)__popcll(m3);
    }
    if (lane == 0) sCnt[w] = cnt;
    __syncthreads();

    int c0 = sCnt[0], c1 = sCnt[1], c2 = sCnt[2], c3 = sCnt[3];
    int base = (w > 0 ? c0 : 0) + (w > 1 ? c1 : 0) + (w > 2 ? c2 : 0);
    int total = c0 + c1 + c2 + c3;
    uint64_t lmask = (1ull << lane) - 1;
    #pragma unroll
    for (int k = 0; k < 32; ++k) {
        int wi = w * 32 + k;
        uint64_t m = sBits[wi];
        if ((m >> lane) & 1) {
            int pos = base + (int)__popcll(m & lmask);
            sIdx[pos] = (uint16_t)(((wi >> 2) << 8) + (lane << 2) + (wi & 3));
        }
        base += (int)__popcll(m);
    }
    int n = total;
    int padded = (n + 15) & ~15;
    if (padded > CAP_E) padded = CAP_E;
    if (w == 3) {
        uint16_t sent = (uint16_t)((NB - b) * N2);
        if (n + lane < padded) sIdx[n + lane] = sent;
    }
    __syncthreads();

    uint64_t* bw = bits + (size_t)row * (N2 / 64);
    if (tid < 128) bw[tid] = sBits[tid];
    const uint32_t* s32 = (const uint32_t*)sIdx;
    uint32_t* o32 = (uint32_t*)(idxE + (size_t)row * CAP_E);
    for (int d = tid; 2 * d < padded; d += 256) o32[d] = s32[d];
    if (tid == 0) cntE[row] = n;
}

// ---------------------------------------------------------------------------
// k_x4t: fused  [0..256) x4 GEMM  |  [256..512) k3 transpose + CSC emit.
// Unchanged from R19.
// ---------------------------------------------------------------------------
union XU {
    struct { float w2s[INF_ * F]; float4 xs4[64 * 32]; } x;   // 64 KB
    struct {
        uint16_t idxn[64][194];   // stride 97 dwords -> conflict-free scatter
        int      pre[8][64];
        int      cnt[64];
    } t;                                                      // ~27 KB
};

__global__ __launch_bounds__(512) void k_x4t(
    const float* __restrict__ x, const float* __restrict__ W2,
    const float* __restrict__ a, const float* __restrict__ a2,
    const float* __restrict__ wctx,
    uint16_t* __restrict__ y16, float* __restrict__ w1, float* __restrict__ q,
    const uint64_t* __restrict__ bits,
    uint16_t* __restrict__ idxN, int* __restrict__ cntN)
{
    __shared__ XU su;
    int tid  = threadIdx.x;
    int lane = tid & 63;
    int w    = tid >> 6;

    if (blockIdx.x < 256) {
        for (int idx = tid; idx < INF_ * F; idx += 512) su.x.w2s[idx] = W2[idx];
        if (blockIdx.x == 0) {
            if (tid < F) y16[(size_t)NB * N2 * F + tid] = 0;   // zero gather row
            if (tid == 0) w1[NB * N2] = 0.f;                   // zero z slot
        }
        {
            const float4* xg4 = (const float4*)(x + (size_t)blockIdx.x * 64 * INF_);
            int r  = tid >> 3;
            int c0 = (tid & 7) * 4;
            #pragma unroll
            for (int i = 0; i < 4; ++i)
                su.x.xs4[r * 32 + c0 + i] = xg4[r * 32 + c0 + i];
        }
        float cpart = wctx[lane] * a[lane];
        #pragma unroll
        for (int s = 32; s; s >>= 1) cpart += __shfl_xor(cpart, s);
        float ax  = a[64 + lane];
        float a2x = a2[lane];
        __syncthreads();

        float acc[8] = {0.f, 0.f, 0.f, 0.f, 0.f, 0.f, 0.f, 0.f};
        for (int k4 = 0; k4 < 32; ++k4) {
            float wk0 = su.x.w2s[(4 * k4 + 0) * F + lane];
            float wk1 = su.x.w2s[(4 * k4 + 1) * F + lane];
            float wk2 = su.x.w2s[(4 * k4 + 2) * F + lane];
            float wk3 = su.x.w2s[(4 * k4 + 3) * F + lane];
            #pragma unroll
            for (int r = 0; r < 8; ++r) {
                float4 xv = su.x.xs4[(8 * w + r) * 32 + k4];   // wave-uniform
                acc[r] = fmaf(xv.x, wk0, acc[r]);
                acc[r] = fmaf(xv.y, wk1, acc[r]);
                acc[r] = fmaf(xv.z, wk2, acc[r]);
                acc[r] = fmaf(xv.w, wk3, acc[r]);
            }
        }
        int row0 = blockIdx.x * 64 + 8 * w;
        #pragma unroll
        for (int r = 0; r < 8; ++r) {
            float acc_ = acc[r];
            float r1 = acc_ * ax, r2 = acc_ * a2x;
            #pragma unroll
            for (int s = 32; s; s >>= 1) { r1 += __shfl_xor(r1, s); r2 += __shfl_xor(r2, s); }
            float s1 = cpart + r1;
            s1 = fmaxf(s1, ALPHA * s1);
            float wv1 = __expf(s1);
            y16[(size_t)(row0 + r) * F + lane] = f2bf(wv1 * acc_);
            if (lane == 0) { w1[row0 + r] = wv1; q[row0 + r] = r2; }
        }
    } else {
        int blk = blockIdx.x - 256;
        int b  = blk >> 7;          // 0..1
        int jw = blk & 127;         // 0..127
        const uint64_t Mtab[6] = {0x00000000FFFFFFFFull, 0x0000FFFF0000FFFFull,
                                  0x00FF00FF00FF00FFull, 0x0F0F0F0F0F0F0F0Full,
                                  0x3333333333333333ull, 0x5555555555555555ull};
        uint64_t wd[4];
        #pragma unroll
        for (int t = 0; t < 4; ++t) {
            int ib = w * 4 + t;
            uint64_t xv = bits[((size_t)(b * N1 + ib * 64 + lane)) * (N2 / 64) + jw];
            #pragma unroll
            for (int st = 0; st < 6; ++st) {
                int s = 32 >> st;
                uint64_t M = Mtab[st];
                uint64_t yy = (uint64_t)__shfl_xor((unsigned long long)xv, s);
                xv = ((lane & s) == 0) ? ((xv & M) | ((yy & M) << s))
                                       : ((xv & ~M) | ((yy & ~M) >> s));
            }
            wd[t] = xv;
        }
        int myc = 0;
        #pragma unroll
        for (int t = 0; t < 4; ++t) myc += (int)__popcll(wd[t]);
        su.t.pre[w][lane] = myc;
        __syncthreads();
        int base = 0, total = 0;
        #pragma unroll
        for (int ww = 0; ww < 8; ++ww) {
            int c = su.t.pre[ww][lane];
            if (ww < w) base += c;
            total += c;
        }
        int n = total < CAP_N ? total : CAP_N;
        if (w == 0) su.t.cnt[lane] = n;

        uint16_t* sr = su.t.idxn[lane];
        int off = base;
        #pragma unroll
        for (int t = 0; t < 4; ++t) {
            uint64_t m = wd[t];
            int ibase = (w * 4 + t) << 6;
            while (m) {
                int ii = __builtin_ctzll(m); m &= m - 1;
                if (off < CAP_N) sr[off] = (uint16_t)(ibase + ii);
                ++off;
            }
        }
        int jp = jw * 64 + lane;                                   // permuted j
        int j  = ((jp >> 8) << 8) + ((jp & 63) << 2) + ((jp >> 6) & 3);  // true j
        int rowOut = b * N2 + j;
        if (w == 7) {
            int padded = (n + 15) & ~15;
            if (padded > CAP_N) padded = CAP_N;
            uint16_t sent = (uint16_t)((NB - b) * N1);
            for (int o = n; o < padded; ++o) sr[o] = sent;
            cntN[rowOut] = n;
        }
        __syncthreads();
        int jbase = b * N2 + ((jw >> 2) << 8) + (jw & 3);
        for (int rr = 0; rr < 8; ++rr) {
            int r = w * 8 + rr;
            int n_r = su.t.cnt[r];
            int padded_r = (n_r + 15) & ~15;
            if (padded_r > CAP_N) padded_r = CAP_N;
            int rowOut_r = jbase + r * 4;
            uint32_t* dst = (uint32_t*)(idxN + (size_t)rowOut_r * CAP_N);
            const uint32_t* src = (const uint32_t*)su.t.idxn[r];
            for (int d = lane; 2 * d < padded_r; d += 64) dst[d] = src[d];
        }
    }
}

// ---------------------------------------------------------------------------
// kD: edge gather + edge@W3 + p.  TWO WAVES PER ROW (even/odd 64-chunks,
// identical R19 chunk shape) -> 8192 waves = 32/CU (was 16, latency-starved;
// kD/kE time ratio 1.9 == occupancy ratio). Pair-reduce via LDS; W3 bf16
// (8 KB, validated R17) keeps LDS at 9.3 KB -> full 8 blocks/CU.
// ---------------------------------------------------------------------------
__global__ __launch_bounds__(256) void kD(
    const uint16_t* __restrict__ idxE, const int* __restrict__ cntE,
    const uint16_t* __restrict__ y16, const float* __restrict__ w1,
    const float* __restrict__ W3, const float* __restrict__ a2,
    float* __restrict__ out_edge, uint16_t* __restrict__ e16, float* __restrict__ p)
{
    __shared__ uint16_t w3h[F * F];   // 8 KB bf16 W3
    __shared__ float4   scr[4][16];   // 1 KB raw acc partials (per wave)
    __shared__ float    zred[4];
    int tid  = threadIdx.x;
    int lane = tid & 63;
    int w    = tid >> 6;
    for (int idx = tid; idx < F * F; idx += 256) w3h[idx] = f2bf(W3[idx]);
    if (blockIdx.x == 0 && tid == 0) p[NB * N1] = -1e30f;   // kE sentinel
    __syncthreads();

    int row  = blockIdx.x * 2 + (w >> 1);      // 2 rows per block
    int half = w & 1;                          // even/odd chunk owner
    int b = row >> 11;
    const uint4* yb = (const uint4*)y16 + (size_t)b * N2 * 8;
    const float* w1b = w1 + (size_t)b * N2;
    const uint16_t* ix = idxE + (size_t)row * CAP_E;
    int g   = lane >> 3;      // 8 groups
    int sub = lane & 7;       // 8 lanes/row, 16 B each
    int n = cntE[row];
    int padded = (n + 15) & ~15;
    if (padded > CAP_E) padded = CAP_E;
    int fullEnd = padded & ~63;
    float4 aA = make_float4(0.f, 0.f, 0.f, 0.f);
    float4 aB = make_float4(0.f, 0.f, 0.f, 0.f);
    float zl = 0.f, zl4 = 0.f;
    for (int t = 64 * half; t + 64 <= fullEnd; t += 128) {   // interleaved chunks
        int myj = ix[t + lane];
        zl += w1b[myj];
        #pragma unroll
        for (int s = 0; s < 8; ++s) {
            int jv = __shfl(myj, 8 * s + g);
            uint4 v = yb[(size_t)jv * 8 + sub];   // 16 B/lane, 8 rows/instr
            aA.x += blo(v.x); aA.y += bhi(v.x);
            aA.z += blo(v.y); aA.w += bhi(v.y);
            aB.x += blo(v.z); aB.y += bhi(v.z);
            aB.z += blo(v.w); aB.w += bhi(v.w);
        }
    }
    if (half == 1) {                                         // 16-granule tail
        for (int t = fullEnd; t < padded; t += 16) {
            int myj = ix[t + (lane & 15)];
            zl4 += w1b[myj];                      // each index counted 4x
            #pragma unroll
            for (int s = 0; s < 2; ++s) {
                int jv = __shfl(myj, 8 * s + g);
                uint4 v = yb[(size_t)jv * 8 + sub];
                aA.x += blo(v.x); aA.y += bhi(v.x);
                aA.z += blo(v.y); aA.w += bhi(v.y);
                aB.x += blo(v.z); aB.y += bhi(v.z);
                aB.z += blo(v.w); aB.w += bhi(v.w);
            }
        }
    }
    #pragma unroll
    for (int s2 = 8; s2 <= 32; s2 <<= 1) {
        aA.x += __shfl_xor(aA.x, s2); aA.y += __shfl_xor(aA.y, s2);
        aA.z += __shfl_xor(aA.z, s2); aA.w += __shfl_xor(aA.w, s2);
        aB.x += __shfl_xor(aB.x, s2); aB.y += __shfl_xor(aB.y, s2);
        aB.z += __shfl_xor(aB.z, s2); aB.w += __shfl_xor(aB.w, s2);
    }
    float zc = zl + 0.25f * zl4;
    #pragma unroll
    for (int s2 = 32; s2; s2 >>= 1) zc += __shfl_xor(zc, s2);
    if (lane < 8) { scr[w][2 * lane] = aA; scr[w][2 * lane + 1] = aB; }
    if (lane == 0) zred[w] = zc;
    __syncthreads();

    if (half == 0) {   // waves 0 and 2 finish their row
        float z = zred[w] + zred[w + 1];
        float inv = 1.f / z;
        if (lane < 16) {
            float4 m0 = scr[w][lane], m1 = scr[w + 1][lane];
            float4 ev = make_float4((m0.x + m1.x) * inv, (m0.y + m1.y) * inv,
                                    (m0.z + m1.z) * inv, (m0.w + m1.w) * inv);
            ((float4*)out_edge)[(size_t)row * 16 + lane] = ev;
            scr[w][lane] = ev;   // combined ev back to wave-local scratch
        }
        float ev = ((const float*)scr[w])[lane];   // feature = lane (intra-wave)
        float a2e = a2[64 + lane];
        float acc4 = 0.f;
        #pragma unroll 8
        for (int gg = 0; gg < 64; ++gg)
            acc4 += __shfl(ev, gg) * bf2f(w3h[gg * F + lane]);
        e16[(size_t)row * F + lane] = f2bf(acc4);  // bf16 copy for kE
        float r = acc4 * a2e;
        #pragma unroll
        for (int s2 = 32; s2; s2 >>= 1) r += __shfl_xor(r, s2);
        if (lane == 0) p[row] = r;
    }
}

// ---------------------------------------------------------------------------
// kE: node[b,j,:] = (sum_i e^{lrelu(p[i]+q[j])} * e16[i,:]) / Z over idxN.
// R19 form (uint4 gathers). Unchanged.
// ---------------------------------------------------------------------------
__global__ __launch_bounds__(256) void kE(
    const uint16_t* __restrict__ idxN, const int* __restrict__ cntN,
    const uint16_t* __restrict__ e16, const float* __restrict__ p,
    const float* __restrict__ q, float* __restrict__ out_node)
{
    int lane = threadIdx.x & 63;
    int g   = lane >> 3;
    int sub = lane & 7;
    int gw = (blockIdx.x * blockDim.x + threadIdx.x) >> 6;
    int nw = (gridDim.x * blockDim.x) >> 6;
    for (int row = gw; row < NB * N2; row += nw) {
        int b = row >> 13;
        const uint4*  eb = (const uint4*)e16 + (size_t)b * N1 * 8;
        const float*  pb = p + b * N1;
        const uint16_t* ix = idxN + (size_t)row * CAP_N;
        float qj = q[row];
        int n = cntN[row];
        int padded = (n + 15) & ~15;
        if (padded > CAP_N) padded = CAP_N;
        float4 aA = make_float4(0.f, 0.f, 0.f, 0.f);
        float4 aB = make_float4(0.f, 0.f, 0.f, 0.f);
        float zl = 0.f, zl4 = 0.f;
        int t = 0;
        for (; t + 64 <= padded; t += 64) {
            int myi = ix[t + lane];
            float sc = pb[myi] + qj;
            sc = fmaxf(sc, ALPHA * sc);
            float wl = __expf(sc);
            zl += wl;
            #pragma unroll
            for (int s = 0; s < 8; ++s) {
                int iv   = __shfl(myi, 8 * s + g);
                float wv = __shfl(wl,  8 * s + g);
                uint4 v = eb[(size_t)iv * 8 + sub];
                aA.x = fmaf(wv, blo(v.x), aA.x); aA.y = fmaf(wv, bhi(v.x), aA.y);
                aA.z = fmaf(wv, blo(v.y), aA.z); aA.w = fmaf(wv, bhi(v.y), aA.w);
                aB.x = fmaf(wv, blo(v.z), aB.x); aB.y = fmaf(wv, bhi(v.z), aB.y);
                aB.z = fmaf(wv, blo(v.w), aB.z); aB.w = fmaf(wv, bhi(v.w), aB.w);
            }
        }
        for (; t < padded; t += 16) {
            int myi = ix[t + (lane & 15)];
            float sc = pb[myi] + qj;
            sc = fmaxf(sc, ALPHA * sc);
            float wl = __expf(sc);
            zl4 += wl;   // each index counted 4x
            #pragma unroll
            for (int s = 0; s < 2; ++s) {
                int iv   = __shfl(myi, 8 * s + g);
                float wv = __shfl(wl,  8 * s + g);
                uint4 v = eb[(size_t)iv * 8 + sub];
                aA.x = fmaf(wv, blo(v.x), aA.x); aA.y = fmaf(wv, bhi(v.x), aA.y);
                aA.z = fmaf(wv, blo(v.y), aA.z); aA.w = fmaf(wv, bhi(v.y), aA.w);
                aB.x = fmaf(wv, blo(v.z), aB.x); aB.y = fmaf(wv, bhi(v.z), aB.y);
                aB.z = fmaf(wv, blo(v.w), aB.z); aB.w = fmaf(wv, bhi(v.w), aB.w);
            }
        }
        #pragma unroll
        for (int s2 = 8; s2 <= 32; s2 <<= 1) {
            aA.x += __shfl_xor(aA.x, s2); aA.y += __shfl_xor(aA.y, s2);
            aA.z += __shfl_xor(aA.z, s2); aA.w += __shfl_xor(aA.w, s2);
            aB.x += __shfl_xor(aB.x, s2); aB.y += __shfl_xor(aB.y, s2);
            aB.z += __shfl_xor(aB.z, s2); aB.w += __shfl_xor(aB.w, s2);
        }
        float zc = zl + 0.25f * zl4;
        #pragma unroll
        for (int s2 = 32; s2; s2 >>= 1) zc += __shfl_xor(zc, s2);
        float inv = 1.f / zc;
        if (lane < 8) {
            float4* o4 = (float4*)out_node + (size_t)row * 16;
            o4[2 * lane]     = make_float4(aA.x * inv, aA.y * inv, aA.z * inv, aA.w * inv);
            o4[2 * lane + 1] = make_float4(aB.x * inv, aB.y * inv, aB.z * inv, aB.w * inv);
        }
    }
}

// ---------------------------------------------------------------------------
extern "C" void kernel_launch(void* const* d_in, const int* in_sizes, int n_in,
                              void* d_out, int out_size, void* d_ws, size_t ws_size,
                              hipStream_t stream)
{
    const float* x    = (const float*)d_in[0];
    const float* adj  = (const float*)d_in[1];
    const float* W2   = (const float*)d_in[2];
    const float* W3   = (const float*)d_in[3];
    const float* a    = (const float*)d_in[4];
    const float* a2   = (const float*)d_in[5];
    const float* wctx = (const float*)d_in[6];

    float* out      = (float*)d_out;
    float* node_out = out;                               // B*N2*F
    float* edge_out = out + (size_t)NB * N2 * F;         // B*N1*F

    // workspace layout (byte offsets, 256B-aligned sections)
    char* basep = (char*)d_ws;
    size_t o = 0;
    uint16_t* y16 = (uint16_t*)(basep + o);               // (NB*N2+1)*F bf16 (+zero row)
    o += (size_t)(NB * N2 + 1) * F * 2;        o = (o + 255) & ~(size_t)255;
    float* w1 = (float*)(basep + o);                      // NB*N2 + 1 (zero slot)
    o += (size_t)(NB * N2 + 4) * 4;            o = (o + 255) & ~(size_t)255;
    float* q = (float*)(basep + o);                       // NB*N2
    o += (size_t)NB * N2 * 4;                  o = (o + 255) & ~(size_t)255;
    uint16_t* e16 = (uint16_t*)(basep + o);               // (NB*N1+1)*F bf16 (+sentinel row)
    o += (size_t)(NB * N1 + 1) * F * 2;        o = (o + 255) & ~(size_t)255;
    float* p = (float*)(basep + o);                       // NB*N1 + 1 (-inf slot)
    o += (size_t)(NB * N1 + 4) * 4;            o = (o + 255) & ~(size_t)255;
    uint64_t* bits = (uint64_t*)(basep + o);              // NB*N1*(N2/64)  (4 MB)
    o += (size_t)NB * N1 * (N2 / 64) * 8;
    int* cntE = (int*)(basep + o);             o += (size_t)NB * N1 * 4;
    int* cntN = (int*)(basep + o);             o += (size_t)NB * N2 * 4;
    uint16_t* idxE = (uint16_t*)(basep + o);   o += (size_t)NB * N1 * CAP_E * 2;
    uint16_t* idxN = (uint16_t*)(basep + o);

    hipLaunchKernelGGL(k_mask_csr, dim3(NB * N1), dim3(256), 0, stream,
                       (const float4*)adj, bits, idxE, cntE);
    hipLaunchKernelGGL(k_x4t, dim3(512), dim3(512), 0, stream,
                       x, W2, a, a2, wctx, y16, w1, q, bits, idxN, cntN);
    hipLaunchKernelGGL(kD, dim3(NB * N1 / 2), dim3(256), 0, stream,
                       idxE, cntE, y16, w1, W3, a2, edge_out, e16, p);
    hipLaunchKernelGGL(kE, dim3(4096), dim3(256), 0, stream,
                       idxN, cntN, e16, p, q, node_out);
}

// Round 21
// 87.695 us; speedup vs baseline: 1.0272x; 1.0272x over previous
//
#include <hip/hip_runtime.h>
#include <stdint.h>

#define NB 2
#define N1 2048
#define N2 8192
#define INF_ 128
#define F 64
#define ALPHA 0.2f
#define CAP_E 640   // per-row capacity (mult of 16); mean 409.6 sd 19.7 (+11.7 sigma)
#define CAP_N 192   // per-col capacity (mult of 16); mean 102.4 sd  9.9

// bf16 helpers
__device__ __forceinline__ float bf2f(unsigned short u) {
    return __uint_as_float((unsigned int)u << 16);
}
__device__ __forceinline__ unsigned short f2bf(float f) {
    unsigned int u = __float_as_uint(f);
    u += 0x7FFF + ((u >> 16) & 1);
    return (unsigned short)(u >> 16);
}
__device__ __forceinline__ float blo(unsigned int d) { return __uint_as_float(d << 16); }
__device__ __forceinline__ float bhi(unsigned int d) { return __uint_as_float(d & 0xFFFF0000u); }

// ---------------------------------------------------------------------------
// k_mask_csr: adj (0/1 fp32, 128 MB) -> bits (permuted words) + idxE + cntE.
// Measured (R13): ~20-25 us warm — at the mandatory adj stream floor.
// ---------------------------------------------------------------------------
__global__ __launch_bounds__(256) void k_mask_csr(
    const float4* __restrict__ adj4, uint64_t* __restrict__ bits,
    uint16_t* __restrict__ idxE, int* __restrict__ cntE)
{
    __shared__ uint64_t sBits[128];
    __shared__ uint16_t sIdx[CAP_E];
    __shared__ int      sCnt[4];
    int tid  = threadIdx.x;
    int lane = tid & 63;
    int w    = tid >> 6;
    int row  = blockIdx.x;               // 4096 blocks = 4096 rows
    int b    = row >> 11;

    const float4* ar = adj4 + (size_t)row * (N2 / 4) + (size_t)w * 512 + lane;
    float4 v[8];
    #pragma unroll
    for (int it = 0; it < 8; ++it) v[it] = ar[it * 64];
    int cnt = 0;
    #pragma unroll
    for (int it = 0; it < 8; ++it) {
        unsigned long long m0 = __ballot(v[it].x != 0.0f);
        unsigned long long m1 = __ballot(v[it].y != 0.0f);
        unsigned long long m2 = __ballot(v[it].z != 0.0f);
        unsigned long long m3 = __ballot(v[it].w != 0.0f);
        if (lane == 0) {
            uint64_t* o = &sBits[w * 32 + it * 4];
            o[0] = m0; o[1] = m1; o[2] = m2; o[3] = m3;
        }
        cnt += (int)__popcll(m0) + (int)__popcll(m1)
             + (int)__popcll(m2) + (int)__popcll(m3);
    }
    if (lane == 0) sCnt[w] = cnt;
    __syncthreads();

    int c0 = sCnt[0], c1 = sCnt[1], c2 = sCnt[2], c3 = sCnt[3];
    int base = (w > 0 ? c0 : 0) + (w > 1 ? c1 : 0) + (w > 2 ? c2 : 0);
    int total = c0 + c1 + c2 + c3;
    uint64_t lmask = (1ull << lane) - 1;
    #pragma unroll
    for (int k = 0; k < 32; ++k) {
        int wi = w * 32 + k;
        uint64_t m = sBits[wi];
        if ((m >> lane) & 1) {
            int pos = base + (int)__popcll(m & lmask);
            sIdx[pos] = (uint16_t)(((wi >> 2) << 8) + (lane << 2) + (wi & 3));
        }
        base += (int)__popcll(m);
    }
    int n = total;
    int padded = (n + 15) & ~15;
    if (padded > CAP_E) padded = CAP_E;
    if (w == 3) {
        uint16_t sent = (uint16_t)((NB - b) * N2);
        if (n + lane < padded) sIdx[n + lane] = sent;
    }
    __syncthreads();

    uint64_t* bw = bits + (size_t)row * (N2 / 64);
    if (tid < 128) bw[tid] = sBits[tid];
    const uint32_t* s32 = (const uint32_t*)sIdx;
    uint32_t* o32 = (uint32_t*)(idxE + (size_t)row * CAP_E);
    for (int d = tid; 2 * d < padded; d += 256) o32[d] = s32[d];
    if (tid == 0) cntE[row] = n;
}

// ---------------------------------------------------------------------------
// k_x4t: fused  [0..256) x4 GEMM  |  [256..512) k3 transpose + CSC emit.
// Unchanged from R19.
// ---------------------------------------------------------------------------
union XU {
    struct { float w2s[INF_ * F]; float4 xs4[64 * 32]; } x;   // 64 KB
    struct {
        uint16_t idxn[64][194];   // stride 97 dwords -> conflict-free scatter
        int      pre[8][64];
        int      cnt[64];
    } t;                                                      // ~27 KB
};

__global__ __launch_bounds__(512) void k_x4t(
    const float* __restrict__ x, const float* __restrict__ W2,
    const float* __restrict__ a, const float* __restrict__ a2,
    const float* __restrict__ wctx,
    uint16_t* __restrict__ y16, float* __restrict__ w1, float* __restrict__ q,
    const uint64_t* __restrict__ bits,
    uint16_t* __restrict__ idxN, int* __restrict__ cntN)
{
    __shared__ XU su;
    int tid  = threadIdx.x;
    int lane = tid & 63;
    int w    = tid >> 6;

    if (blockIdx.x < 256) {
        for (int idx = tid; idx < INF_ * F; idx += 512) su.x.w2s[idx] = W2[idx];
        if (blockIdx.x == 0) {
            if (tid < F) y16[(size_t)NB * N2 * F + tid] = 0;   // zero gather row
            if (tid == 0) w1[NB * N2] = 0.f;                   // zero z slot
        }
        {
            const float4* xg4 = (const float4*)(x + (size_t)blockIdx.x * 64 * INF_);
            int r  = tid >> 3;
            int c0 = (tid & 7) * 4;
            #pragma unroll
            for (int i = 0; i < 4; ++i)
                su.x.xs4[r * 32 + c0 + i] = xg4[r * 32 + c0 + i];
        }
        float cpart = wctx[lane] * a[lane];
        #pragma unroll
        for (int s = 32; s; s >>= 1) cpart += __shfl_xor(cpart, s);
        float ax  = a[64 + lane];
        float a2x = a2[lane];
        __syncthreads();

        float acc[8] = {0.f, 0.f, 0.f, 0.f, 0.f, 0.f, 0.f, 0.f};
        for (int k4 = 0; k4 < 32; ++k4) {
            float wk0 = su.x.w2s[(4 * k4 + 0) * F + lane];
            float wk1 = su.x.w2s[(4 * k4 + 1) * F + lane];
            float wk2 = su.x.w2s[(4 * k4 + 2) * F + lane];
            float wk3 = su.x.w2s[(4 * k4 + 3) * F + lane];
            #pragma unroll
            for (int r = 0; r < 8; ++r) {
                float4 xv = su.x.xs4[(8 * w + r) * 32 + k4];   // wave-uniform
                acc[r] = fmaf(xv.x, wk0, acc[r]);
                acc[r] = fmaf(xv.y, wk1, acc[r]);
                acc[r] = fmaf(xv.z, wk2, acc[r]);
                acc[r] = fmaf(xv.w, wk3, acc[r]);
            }
        }
        int row0 = blockIdx.x * 64 + 8 * w;
        #pragma unroll
        for (int r = 0; r < 8; ++r) {
            float acc_ = acc[r];
            float r1 = acc_ * ax, r2 = acc_ * a2x;
            #pragma unroll
            for (int s = 32; s; s >>= 1) { r1 += __shfl_xor(r1, s); r2 += __shfl_xor(r2, s); }
            float s1 = cpart + r1;
            s1 = fmaxf(s1, ALPHA * s1);
            float wv1 = __expf(s1);
            y16[(size_t)(row0 + r) * F + lane] = f2bf(wv1 * acc_);
            if (lane == 0) { w1[row0 + r] = wv1; q[row0 + r] = r2; }
        }
    } else {
        int blk = blockIdx.x - 256;
        int b  = blk >> 7;          // 0..1
        int jw = blk & 127;         // 0..127
        const uint64_t Mtab[6] = {0x00000000FFFFFFFFull, 0x0000FFFF0000FFFFull,
                                  0x00FF00FF00FF00FFull, 0x0F0F0F0F0F0F0F0Full,
                                  0x3333333333333333ull, 0x5555555555555555ull};
        uint64_t wd[4];
        #pragma unroll
        for (int t = 0; t < 4; ++t) {
            int ib = w * 4 + t;
            uint64_t xv = bits[((size_t)(b * N1 + ib * 64 + lane)) * (N2 / 64) + jw];
            #pragma unroll
            for (int st = 0; st < 6; ++st) {
                int s = 32 >> st;
                uint64_t M = Mtab[st];
                uint64_t yy = (uint64_t)__shfl_xor((unsigned long long)xv, s);
                xv = ((lane & s) == 0) ? ((xv & M) | ((yy & M) << s))
                                       : ((xv & ~M) | ((yy & ~M) >> s));
            }
            wd[t] = xv;
        }
        int myc = 0;
        #pragma unroll
        for (int t = 0; t < 4; ++t) myc += (int)__popcll(wd[t]);
        su.t.pre[w][lane] = myc;
        __syncthreads();
        int base = 0, total = 0;
        #pragma unroll
        for (int ww = 0; ww < 8; ++ww) {
            int c = su.t.pre[ww][lane];
            if (ww < w) base += c;
            total += c;
        }
        int n = total < CAP_N ? total : CAP_N;
        if (w == 0) su.t.cnt[lane] = n;

        uint16_t* sr = su.t.idxn[lane];
        int off = base;
        #pragma unroll
        for (int t = 0; t < 4; ++t) {
            uint64_t m = wd[t];
            int ibase = (w * 4 + t) << 6;
            while (m) {
                int ii = __builtin_ctzll(m); m &= m - 1;
                if (off < CAP_N) sr[off] = (uint16_t)(ibase + ii);
                ++off;
            }
        }
        int jp = jw * 64 + lane;                                   // permuted j
        int j  = ((jp >> 8) << 8) + ((jp & 63) << 2) + ((jp >> 6) & 3);  // true j
        int rowOut = b * N2 + j;
        if (w == 7) {
            int padded = (n + 15) & ~15;
            if (padded > CAP_N) padded = CAP_N;
            uint16_t sent = (uint16_t)((NB - b) * N1);
            for (int o = n; o < padded; ++o) sr[o] = sent;
            cntN[rowOut] = n;
        }
        __syncthreads();
        int jbase = b * N2 + ((jw >> 2) << 8) + (jw & 3);
        for (int rr = 0; rr < 8; ++rr) {
            int r = w * 8 + rr;
            int n_r = su.t.cnt[r];
            int padded_r = (n_r + 15) & ~15;
            if (padded_r > CAP_N) padded_r = CAP_N;
            int rowOut_r = jbase + r * 4;
            uint32_t* dst = (uint32_t*)(idxN + (size_t)rowOut_r * CAP_N);
            const uint32_t* src = (const uint32_t*)su.t.idxn[r];
            for (int d = lane; 2 * d < padded_r; d += 64) dst[d] = src[d];
        }
    }
}

// ---------------------------------------------------------------------------
// kD: edge gather + edge@W3 + p. R19 + next-chunk idx/w1 prefetch pipeline.
// ---------------------------------------------------------------------------
__global__ __launch_bounds__(256) void kD(
    const uint16_t* __restrict__ idxE, const int* __restrict__ cntE,
    const uint16_t* __restrict__ y16, const float* __restrict__ w1,
    const float* __restrict__ W3, const float* __restrict__ a2,
    float* __restrict__ out_edge, uint16_t* __restrict__ e16, float* __restrict__ p)
{
    __shared__ float  w3s[F * F];     // 16 KB
    __shared__ float4 scr4[4][16];    // 1 KB per-wave ev scratch
    int tid  = threadIdx.x;
    int lane = tid & 63;
    int w    = tid >> 6;
    for (int idx = tid; idx < F * F; idx += 256) w3s[idx] = W3[idx];
    if (blockIdx.x == 0 && tid == 0) p[NB * N1] = -1e30f;   // kE sentinel
    __syncthreads();
    int g   = lane >> 3;      // 8 groups
    int sub = lane & 7;       // 8 lanes/row, 16 B each
    int row = (blockIdx.x * 256 + tid) >> 6;   // 1 row per wave
    int b = row >> 11;
    const uint4* yb = (const uint4*)y16 + (size_t)b * N2 * 8;
    const float* w1b = w1 + (size_t)b * N2;
    const uint16_t* ix = idxE + (size_t)row * CAP_E;
    int n = cntE[row];
    int padded = (n + 15) & ~15;
    if (padded > CAP_E) padded = CAP_E;
    int fullEnd = padded & ~63;
    float4 aA = make_float4(0.f, 0.f, 0.f, 0.f);
    float4 aB = make_float4(0.f, 0.f, 0.f, 0.f);
    float zl = 0.f, zl4 = 0.f;
    int myj = 0; float wv = 0.f;
    if (fullEnd > 0) { myj = ix[lane]; wv = w1b[myj]; }
    for (int t = 0; t < fullEnd; t += 64) {
        int myj_n = 0; float wv_n = 0.f;
        int tn = t + 64;
        if (tn < fullEnd) { myj_n = ix[tn + lane]; wv_n = w1b[myj_n]; }
        zl += wv;
        #pragma unroll
        for (int s = 0; s < 8; ++s) {
            int jv = __shfl(myj, 8 * s + g);
            uint4 v = yb[(size_t)jv * 8 + sub];   // 16 B/lane, 8 rows/instr
            aA.x += blo(v.x); aA.y += bhi(v.x);
            aA.z += blo(v.y); aA.w += bhi(v.y);
            aB.x += blo(v.z); aB.y += bhi(v.z);
            aB.z += blo(v.w); aB.w += bhi(v.w);
        }
        myj = myj_n; wv = wv_n;
    }
    for (int t = fullEnd; t < padded; t += 16) {
        int mj = ix[t + (lane & 15)];
        zl4 += w1b[mj];                       // each index counted 4x
        #pragma unroll
        for (int s = 0; s < 2; ++s) {
            int jv = __shfl(mj, 8 * s + g);
            uint4 v = yb[(size_t)jv * 8 + sub];
            aA.x += blo(v.x); aA.y += bhi(v.x);
            aA.z += blo(v.y); aA.w += bhi(v.y);
            aB.x += blo(v.z); aB.y += bhi(v.z);
            aB.z += blo(v.w); aB.w += bhi(v.w);
        }
    }
    #pragma unroll
    for (int s2 = 8; s2 <= 32; s2 <<= 1) {
        aA.x += __shfl_xor(aA.x, s2); aA.y += __shfl_xor(aA.y, s2);
        aA.z += __shfl_xor(aA.z, s2); aA.w += __shfl_xor(aA.w, s2);
        aB.x += __shfl_xor(aB.x, s2); aB.y += __shfl_xor(aB.y, s2);
        aB.z += __shfl_xor(aB.z, s2); aB.w += __shfl_xor(aB.w, s2);
    }
    float zc = zl + 0.25f * zl4;
    #pragma unroll
    for (int s2 = 32; s2; s2 >>= 1) zc += __shfl_xor(zc, s2);
    float inv = 1.f / zc;
    float4 evA = make_float4(aA.x * inv, aA.y * inv, aA.z * inv, aA.w * inv);
    float4 evB = make_float4(aB.x * inv, aB.y * inv, aB.z * inv, aB.w * inv);
    if (lane < 8) {
        float4* o4 = (float4*)out_edge + (size_t)row * 16;
        o4[2 * lane]     = evA;
        o4[2 * lane + 1] = evB;
        scr4[w][2 * lane]     = evA;
        scr4[w][2 * lane + 1] = evB;
    }
    float ev = ((const float*)scr4[w])[lane]; // feature = lane (same-wave LDS)
    float a2e = a2[64 + lane];
    float acc4 = 0.f;
    #pragma unroll 8
    for (int gg = 0; gg < 64; ++gg) acc4 += __shfl(ev, gg) * w3s[gg * F + lane];
    e16[(size_t)row * F + lane] = f2bf(acc4);
    float r = acc4 * a2e;
    #pragma unroll
    for (int s2 = 32; s2; s2 >>= 1) r += __shfl_xor(r, s2);
    if (lane == 0) p[row] = r;
}

// ---------------------------------------------------------------------------
// kE: node gather over idxN. R19 + next-chunk idx/p prefetch pipeline.
// ---------------------------------------------------------------------------
__global__ __launch_bounds__(256) void kE(
    const uint16_t* __restrict__ idxN, const int* __restrict__ cntN,
    const uint16_t* __restrict__ e16, const float* __restrict__ p,
    const float* __restrict__ q, float* __restrict__ out_node)
{
    int lane = threadIdx.x & 63;
    int g   = lane >> 3;
    int sub = lane & 7;
    int gw = (blockIdx.x * blockDim.x + threadIdx.x) >> 6;
    int nw = (gridDim.x * blockDim.x) >> 6;
    for (int row = gw; row < NB * N2; row += nw) {
        int b = row >> 13;
        const uint4*  eb = (const uint4*)e16 + (size_t)b * N1 * 8;
        const float*  pb = p + b * N1;
        const uint16_t* ix = idxN + (size_t)row * CAP_N;
        float qj = q[row];
        int n = cntN[row];
        int padded = (n + 15) & ~15;
        if (padded > CAP_N) padded = CAP_N;
        int fullEnd = padded & ~63;
        float4 aA = make_float4(0.f, 0.f, 0.f, 0.f);
        float4 aB = make_float4(0.f, 0.f, 0.f, 0.f);
        float zl = 0.f, zl4 = 0.f;
        int myi = 0; float pv = 0.f;
        if (fullEnd > 0) { myi = ix[lane]; pv = pb[myi]; }
        for (int t = 0; t < fullEnd; t += 64) {
            int myi_n = 0; float pv_n = 0.f;
            int tn = t + 64;
            if (tn < fullEnd) { myi_n = ix[tn + lane]; pv_n = pb[myi_n]; }
            float sc = pv + qj;
            sc = fmaxf(sc, ALPHA * sc);
            float wl = __expf(sc);
            zl += wl;
            #pragma unroll
            for (int s = 0; s < 8; ++s) {
                int iv   = __shfl(myi, 8 * s + g);
                float wv = __shfl(wl,  8 * s + g);
                uint4 v = eb[(size_t)iv * 8 + sub];
                aA.x = fmaf(wv, blo(v.x), aA.x); aA.y = fmaf(wv, bhi(v.x), aA.y);
                aA.z = fmaf(wv, blo(v.y), aA.z); aA.w = fmaf(wv, bhi(v.y), aA.w);
                aB.x = fmaf(wv, blo(v.z), aB.x); aB.y = fmaf(wv, bhi(v.z), aB.y);
                aB.z = fmaf(wv, blo(v.w), aB.z); aB.w = fmaf(wv, bhi(v.w), aB.w);
            }
            myi = myi_n; pv = pv_n;
        }
        for (int t = fullEnd; t < padded; t += 16) {
            int mi = ix[t + (lane & 15)];
            float sc = pb[mi] + qj;
            sc = fmaxf(sc, ALPHA * sc);
            float wl = __expf(sc);
            zl4 += wl;   // each index counted 4x
            #pragma unroll
            for (int s = 0; s < 2; ++s) {
                int iv   = __shfl(mi, 8 * s + g);
                float wv = __shfl(wl,  8 * s + g);
                uint4 v = eb[(size_t)iv * 8 + sub];
                aA.x = fmaf(wv, blo(v.x), aA.x); aA.y = fmaf(wv, bhi(v.x), aA.y);
                aA.z = fmaf(wv, blo(v.y), aA.z); aA.w = fmaf(wv, bhi(v.y), aA.w);
                aB.x = fmaf(wv, blo(v.z), aB.x); aB.y = fmaf(wv, bhi(v.z), aB.y);
                aB.z = fmaf(wv, blo(v.w), aB.z); aB.w = fmaf(wv, bhi(v.w), aB.w);
            }
        }
        #pragma unroll
        for (int s2 = 8; s2 <= 32; s2 <<= 1) {
            aA.x += __shfl_xor(aA.x, s2); aA.y += __shfl_xor(aA.y, s2);
            aA.z += __shfl_xor(aA.z, s2); aA.w += __shfl_xor(aA.w, s2);
            aB.x += __shfl_xor(aB.x, s2); aB.y += __shfl_xor(aB.y, s2);
            aB.z += __shfl_xor(aB.z, s2); aB.w += __shfl_xor(aB.w, s2);
        }
        float zc = zl + 0.25f * zl4;
        #pragma unroll
        for (int s2 = 32; s2; s2 >>= 1) zc += __shfl_xor(zc, s2);
        float inv = 1.f / zc;
        if (lane < 8) {
            float4* o4 = (float4*)out_node + (size_t)row * 16;
            o4[2 * lane]     = make_float4(aA.x * inv, aA.y * inv, aA.z * inv, aA.w * inv);
            o4[2 * lane + 1] = make_float4(aB.x * inv, aB.y * inv, aB.z * inv, aB.w * inv);
        }
    }
}

// ---------------------------------------------------------------------------
extern "C" void kernel_launch(void* const* d_in, const int* in_sizes, int n_in,
                              void* d_out, int out_size, void* d_ws, size_t ws_size,
                              hipStream_t stream)
{
    const float* x    = (const float*)d_in[0];
    const float* adj  = (const float*)d_in[1];
    const float* W2   = (const float*)d_in[2];
    const float* W3   = (const float*)d_in[3];
    const float* a    = (const float*)d_in[4];
    const float* a2   = (const float*)d_in[5];
    const float* wctx = (const float*)d_in[6];

    float* out      = (float*)d_out;
    float* node_out = out;                               // B*N2*F
    float* edge_out = out + (size_t)NB * N2 * F;         // B*N1*F

    // workspace layout (byte offsets, 256B-aligned sections)
    char* basep = (char*)d_ws;
    size_t o = 0;
    uint16_t* y16 = (uint16_t*)(basep + o);               // (NB*N2+1)*F bf16 (+zero row)
    o += (size_t)(NB * N2 + 1) * F * 2;        o = (o + 255) & ~(size_t)255;
    float* w1 = (float*)(basep + o);                      // NB*N2 + 1 (zero slot)
    o += (size_t)(NB * N2 + 4) * 4;            o = (o + 255) & ~(size_t)255;
    float* q = (float*)(basep + o);                       // NB*N2
    o += (size_t)NB * N2 * 4;                  o = (o + 255) & ~(size_t)255;
    uint16_t* e16 = (uint16_t*)(basep + o);               // (NB*N1+1)*F bf16 (+sentinel row)
    o += (size_t)(NB * N1 + 1) * F * 2;        o = (o + 255) & ~(size_t)255;
    float* p = (float*)(basep + o);                       // NB*N1 + 1 (-inf slot)
    o += (size_t)(NB * N1 + 4) * 4;            o = (o + 255) & ~(size_t)255;
    uint64_t* bits = (uint64_t*)(basep + o);              // NB*N1*(N2/64)  (4 MB)
    o += (size_t)NB * N1 * (N2 / 64) * 8;
    int* cntE = (int*)(basep + o);             o += (size_t)NB * N1 * 4;
    int* cntN = (int*)(basep + o);             o += (size_t)NB * N2 * 4;
    uint16_t* idxE = (uint16_t*)(basep + o);   o += (size_t)NB * N1 * CAP_E * 2;
    uint16_t* idxN = (uint16_t*)(basep + o);

    hipLaunchKernelGGL(k_mask_csr, dim3(NB * N1), dim3(256), 0, stream,
                       (const float4*)adj, bits, idxE, cntE);
    hipLaunchKernelGGL(k_x4t, dim3(512), dim3(512), 0, stream,
                       x, W2, a, a2, wctx, y16, w1, q, bits, idxN, cntN);
    hipLaunchKernelGGL(kD, dim3(NB * N1 / 4), dim3(256), 0, stream,
                       idxE, cntE, y16, w1, W3, a2, edge_out, e16, p);
    hipLaunchKernelGGL(kE, dim3(4096), dim3(256), 0, stream,
                       idxN, cntN, e16, p, q, node_out);
}